// Round 1
// baseline (375.668 us; speedup 1.0000x reference)
//
#include <hip/hip_runtime.h>
#include <stdint.h>

#define BB 512
#define TT 1024
#define KK 48
#define PF 8

// mask may arrive as 1-byte bools (raw numpy) or as 4-byte words.
// mask[0][0..3] are guaranteed true (len >= T/2), so the first 32-bit word is
// 0x01010101 iff byte storage.
__device__ __forceinline__ int mask_at(const void* m, int idx, bool bytes) {
    return bytes ? (int)(((const uint8_t*)m)[idx] != 0)
                 : (int)(((const int*)m)[idx] != 0);
}

// wave-uniform broadcast from a fixed lane (used once for init)
__device__ __forceinline__ float bcast(float v, int lane) {
    return __int_as_float(__builtin_amdgcn_readlane(__float_as_int(v), lane));
}

// ------------- forward algorithm + fused gold-path score -------------------
// One wave per batch row; lane j owns state j. Exp-domain recurrence
// p <- (E^T p) * exp(em_t), E = exp(trans) in VGPRs.
//
// R5: the 48x v_readlane broadcast storm was ~60% of the step (each readlane
// is a VALU op writing an SGPR; 48 back-to-back VALU->SGPR writes serialize
// at ~4-6 cyc each => ~514 cyc/step measured vs ~220 issue-model).
// Replace with LDS broadcast: 1x ds_write_b32 (lane j publishes p[j]) +
// 12x uniform-address ds_read_b128 (bank broadcast, conflict-free, 4 values
// per instr, results in VGPRs). FMAs become all-VGPR (no SGPR hazards) and
// the broadcast moves off the VALU pipe. Single wave per block => no barrier;
// same-wave DS ops are processed in order by the LDS pipe; compile fences
// pin the write<->read program order.
// Renorm every 4th step: growth/step <= 48*e^{0.1+5.5} ~= 2^14 — f32-safe.
__global__ __launch_bounds__(64, 1) void crf_fwd(
    const float* __restrict__ em, const int* __restrict__ tags,
    const void* __restrict__ mask, const float* __restrict__ trans,
    const float* __restrict__ start, const float* __restrict__ endt,
    float* __restrict__ ws)
{
    __shared__ __align__(16) float plds[64];

    const int b = blockIdx.x;
    const int lane = threadIdx.x;
    const bool active = lane < KK;
    const int j = active ? lane : KK - 1;   // clamp for safe loads

    const bool mb = (*(const int*)mask) == 0x01010101;

    // sequence length = popcount of prefix mask
    int cnt = 0;
    for (int t = lane; t < TT; t += 64) cnt += mask_at(mask, b * TT + t, mb);
    #pragma unroll
    for (int off = 32; off >= 1; off >>= 1) cnt += __shfl_xor(cnt, off);
    const int len = cnt;

    // E[i][j] = exp(trans[i][j]) for this lane's column j
    float etr[KK];
    #pragma unroll
    for (int i = 0; i < KK; ++i) {
        etr[i] = active ? __expf(trans[i * KK + j]) : 0.0f;
        asm volatile("" : "+v"(etr[i]));
    }

    const float* emb = em + (size_t)b * TT * KK;

    // init: pcur = exp(S_0 - c), c = S_0[0]
    float s0 = start[j] + emb[j];
    float c = bcast(s0, 0);
    float pcur = active ? __expf(s0 - c) : 0.0f;

    plds[lane] = pcur;              // publish p for step t=1

    // emission prefetch pipeline (depth PF) keeps HBM/L2 latency off the chain
    float pipe[PF];
    #pragma unroll
    for (int d = 0; d < PF; ++d) pipe[d] = emb[(1 + d) * KK + j];

    int t = 1;
    // ---- main loop: full PF-blocks, no per-substep guards ----
    while (t + PF <= len) {
        float eexp[PF];
        #pragma unroll
        for (int d = 0; d < PF; ++d) eexp[d] = __expf(pipe[d]);   // off-chain
        #pragma unroll
        for (int d = 0; d < PF; ++d) {
            int tt = t + PF + d; tt = tt < TT ? tt : TT - 1;
            pipe[d] = emb[tt * KK + j];
        }
        #pragma unroll
        for (int d = 0; d < PF; ++d) {
            // broadcast p via LDS: 12x uniform-addr ds_read_b128
            asm volatile("" ::: "memory");   // keep reads after prev ds_write
            float s[KK];
            #pragma unroll
            for (int k = 0; k < KK; k += 4) {
                float4 v4 = *(const float4*)(plds + k);
                s[k]     = v4.x;
                s[k + 1] = v4.y;
                s[k + 2] = v4.z;
                s[k + 3] = v4.w;
            }
            float scale = eexp[d];
            const bool renorm = (d == 0) || (d == 4);
            if (renorm) scale *= __builtin_amdgcn_rcpf(s[0]);
            float q0 = s[0] * etr[0];
            float q1 = s[1] * etr[1];
            float q2 = s[2] * etr[2];
            float q3 = s[3] * etr[3];
            #pragma unroll
            for (int k = 4; k < KK; k += 4) {
                q0 = fmaf(s[k],     etr[k],     q0);
                q1 = fmaf(s[k + 1], etr[k + 1], q1);
                q2 = fmaf(s[k + 2], etr[k + 2], q2);
                q3 = fmaf(s[k + 3], etr[k + 3], q3);
            }
            if (renorm) c += __logf(s[0]);          // side chain
            float qs = (q0 + q1) + (q2 + q3);
            pcur = qs * scale;
            asm volatile("" ::: "memory");   // keep write after reads
            plds[lane] = pcur;               // publish p for next step
        }
        t += PF;
    }
    // ---- tail: guarded, renorm every step (<= 7 steps) ----
    while (t < len) {
        float e = __expf(pipe[0]);
        #pragma unroll
        for (int d = 0; d < PF - 1; ++d) pipe[d] = pipe[d + 1];
        {
            asm volatile("" ::: "memory");
            float s[KK];
            #pragma unroll
            for (int k = 0; k < KK; k += 4) {
                float4 v4 = *(const float4*)(plds + k);
                s[k]     = v4.x;
                s[k + 1] = v4.y;
                s[k + 2] = v4.z;
                s[k + 3] = v4.w;
            }
            float scale = e * __builtin_amdgcn_rcpf(s[0]);
            float q0 = s[0] * etr[0];
            float q1 = s[1] * etr[1];
            float q2 = s[2] * etr[2];
            float q3 = s[3] * etr[3];
            #pragma unroll
            for (int k = 4; k < KK; k += 4) {
                q0 = fmaf(s[k],     etr[k],     q0);
                q1 = fmaf(s[k + 1], etr[k + 1], q1);
                q2 = fmaf(s[k + 2], etr[k + 2], q2);
                q3 = fmaf(s[k + 3], etr[k + 3], q3);
            }
            c += __logf(s[0]);
            float qs = (q0 + q1) + (q2 + q3);
            pcur = qs * scale;
            asm volatile("" ::: "memory");
            plds[lane] = pcur;
        }
        ++t;
    }

    // log_z = c + log(sum_j pcur_j * exp(end_j))
    float v = active ? pcur * __expf(endt[j]) : 0.0f;
    #pragma unroll
    for (int off = 32; off >= 1; off >>= 1) v += __shfl_xor(v, off);

    // ---- fused gold-path score (mask is prefix: m[t] == (t < len)) ----
    const int* tgb = tags + b * TT;
    float sq = 0.f;
    for (int tt2 = lane; tt2 < TT; tt2 += 64) {
        if (tt2 >= 1 && tt2 < len) {
            int tp = tgb[tt2 - 1], tc = tgb[tt2];
            sq += trans[tp * KK + tc] + emb[tt2 * KK + tc];
        }
    }
    #pragma unroll
    for (int off = 32; off >= 1; off >>= 1) sq += __shfl_xor(sq, off);

    if (lane == 0) {
        int t0 = tgb[0];
        ws[b]      = c + __logf(v);
        ws[BB + b] = sq + start[t0] + emb[t0] + endt[tgb[len - 1]];
    }
}

// ---------------- final mean reduction ----------------
__global__ __launch_bounds__(256) void crf_final(const float* __restrict__ ws,
                                                 float* __restrict__ out)
{
    __shared__ float red[256];
    float s = 0.f;
    for (int b = threadIdx.x; b < BB; b += 256) s += ws[b] - ws[BB + b];
    red[threadIdx.x] = s;
    __syncthreads();
    for (int off = 128; off > 0; off >>= 1) {
        if (threadIdx.x < off) red[threadIdx.x] += red[threadIdx.x + off];
        __syncthreads();
    }
    if (threadIdx.x == 0) out[0] = red[0] / (float)BB;
}

extern "C" void kernel_launch(void* const* d_in, const int* in_sizes, int n_in,
                              void* d_out, int out_size, void* d_ws, size_t ws_size,
                              hipStream_t stream) {
    const float* em    = (const float*)d_in[0];
    const int*   tags  = (const int*)d_in[1];
    const void*  mask  = d_in[2];
    const float* trans = (const float*)d_in[3];
    const float* start = (const float*)d_in[4];
    const float* endt  = (const float*)d_in[5];
    float* ws  = (float*)d_ws;
    float* out = (float*)d_out;

    crf_fwd  <<<BB, 64,  0, stream>>>(em, tags, mask, trans, start, endt, ws);
    crf_final<<<1,  256, 0, stream>>>(ws, out);
}